// Round 2
// baseline (80.293 us; speedup 1.0000x reference)
//
#include <hip/hip_runtime.h>

// InnerProductNetwork: x (B, 32, 16) fp32 -> out (B, 496) fp32
// out[b] = upper triangle of G = X @ X^T, X = x[b] (32x16), via one
// v_mfma_f32_32x32x16_bf16 per batch (A-frag == B-frag for X@X^T).
//
// Round-1 change: MLP fix. Round-0 issued 2 loads/wave then vmcnt(0)-waited
// immediately -> 512 B in flight/CU vs ~9.2 KB needed (Little's law at
// 900 cyc latency, 10.25 B/cyc/CU HBM share) -> load-latency bound (~80 us).
// Now: 4 batches/wave, all 8 dwordx4 loads hoisted before any use; grid
// 1024 = 4 blocks/CU resident, so ~128 KB/CU of reads are queued up front
// and DRAM streams at full BW. Scatter addresses are batch-invariant and
// computed once (cndmask to trash slot replaces 16x exec-mask predication).

typedef short bf16x8 __attribute__((ext_vector_type(8)));
typedef float f32x16 __attribute__((ext_vector_type(16)));

#define NPAIR   496            // 32*31/2
#define BATCH_F 512            // floats per batch (32 fields x 16 dim)
#define GB      4              // batches per wave
#define SUB     512            // dwords per batch sub-slice (496 data + 16 trash)
#define SLICE   (GB * SUB)     // 2048 dwords per wave slice

// fp32 -> bf16 round-to-nearest-even (inputs finite normals; no NaN path)
static __device__ __forceinline__ unsigned short f2bf(float f) {
  unsigned u = __float_as_uint(f);
  u += 0x7FFFu + ((u >> 16) & 1u);
  return (unsigned short)(u >> 16);
}

__global__ __launch_bounds__(256, 4)
void ipnn_mfma(const float* __restrict__ x, float* __restrict__ out, int nb) {
  __shared__ __align__(16) float so[4 * SLICE];   // 32 KB/block -> 4 blocks/CU
  const int wave = threadIdx.x >> 6;
  const int lane = threadIdx.x & 63;
  const int m = lane & 31;               // field row this lane loads (= Gram col)
  const int h = lane >> 5;               // k-half: 0 -> k=0..7, 1 -> k=8..15
  const long b0 = ((long)blockIdx.x * 4 + wave) * GB;

  // ---- all global loads issued up front: 8 dwordx4 in flight per wave ----
  float4 f[GB][2];
  const int fi = m * 4 + h * 2;          // float4 index within batch
#pragma unroll
  for (int t = 0; t < GB; ++t) {
    long bt = b0 + t;
    if (bt >= nb) bt = nb - 1;           // clamp (grid is exact; safety only)
    const float4* gp = (const float4*)(x + bt * BATCH_F);
    f[t][0] = gp[fi];
    f[t][1] = gp[fi + 1];
  }

  // ---- batch-invariant scatter addresses, computed once per wave ----
  // C/D layout (m74/m101): col = lane&31, row = (r&3) + 8*(r>>2) + 4*h.
  // G symmetric -> row/col swap immune. Invalid (row>=col) entries are
  // redirected to a trash region via cndmask instead of exec-mask branches.
  float* sw = so + wave * SLICE;
  int addr[16];
#pragma unroll
  for (int r = 0; r < 16; ++r) {
    const int row = (r & 3) + 8 * (r >> 2) + 4 * h;
    const int pidx = ((row * (63 - row)) >> 1) + (m - row - 1);
    addr[r] = (row < m) ? pidx : (NPAIR + (lane & 15));   // trash: 496..511
  }

  // ---- per-batch: convert, MFMA, unconditional LDS scatter ----
#pragma unroll
  for (int t = 0; t < GB; ++t) {
    bf16x8 a;
    a[0] = (short)f2bf(f[t][0].x);
    a[1] = (short)f2bf(f[t][0].y);
    a[2] = (short)f2bf(f[t][0].z);
    a[3] = (short)f2bf(f[t][0].w);
    a[4] = (short)f2bf(f[t][1].x);
    a[5] = (short)f2bf(f[t][1].y);
    a[6] = (short)f2bf(f[t][1].z);
    a[7] = (short)f2bf(f[t][1].w);

    f32x16 acc = {};
    acc = __builtin_amdgcn_mfma_f32_32x32x16_bf16(a, a, acc, 0, 0, 0);

    float* sb = sw + t * SUB;            // t*SUB folds into ds_write imm offset
#pragma unroll
    for (int r = 0; r < 16; ++r) {
      sb[addr[r]] = acc[r];
    }
  }

  __syncthreads();  // cross-lane LDS visibility (uniform; all waves reach it)

  // ---- coalesced readback + store: per batch 62 lanes x 2 float4 ----
  if (lane < 62) {
#pragma unroll
    for (int t = 0; t < GB; ++t) {
      const long bt = b0 + t;
      if (bt >= nb) continue;
      const float* sb = sw + t * SUB;
      float4 v0 = *(const float4*)(sb + 4 * lane);         // dwords [0,248)
      float4 v1 = *(const float4*)(sb + 4 * lane + 248);   // dwords [248,496)
      float4* op = (float4*)(out + bt * NPAIR);
      op[lane] = v0;
      op[lane + 62] = v1;
    }
  }
}

extern "C" void kernel_launch(void* const* d_in, const int* in_sizes, int n_in,
                              void* d_out, int out_size, void* d_ws, size_t ws_size,
                              hipStream_t stream) {
  const float* x = (const float*)d_in[0];
  float* out = (float*)d_out;
  const int nb = in_sizes[0] / BATCH_F;       // 16384
  const int grid = (nb + GB * 4 - 1) / (GB * 4);   // 16 batches/block -> 1024
  ipnn_mfma<<<grid, 256, 0, stream>>>(x, out, nb);
}

// Round 4
// 80.004 us; speedup vs baseline: 1.0036x; 1.0036x over previous
//
#include <hip/hip_runtime.h>

// InnerProductNetwork: x (B, 32, 16) fp32 -> out (B, 496) fp32
// out[b] = upper triangle of G = X @ X^T, X = x[b] (32x16), via one
// v_mfma_f32_32x32x16_bf16 per batch (A-frag == B-frag for X@X^T).
//
// Round-2 analysis: dur_us (~80) = ~60 us of serialized harness ops
// (256 MiB d_ws poison @43.9us + d_in restore + d_out poison) + ~15-20 us
// kernel term (kernel absent from top-5 => <43.4 us dispatch). Kernel HBM
// floor = 66 MB / 6.3 TB/s ~ 11 us. This round attacks the kernel-term gap:
//  (a) drop __syncthreads - each wave only touches its OWN LDS slice, so the
//      barrier only serialized 4 waves on the block's slowest load arrivals;
//  (b) non-temporal output stores (write stream never re-read by kernel).
// Round-3 fix: __builtin_nontemporal_store needs a native clang vector type,
// not HIP's float4 class -> use ext_vector_type(4) float for readback/store.
// Decision rule: dur_us unchanged (+-1.5) => kernel at floor, harness-const
// dominated => declare roofline.

typedef short bf16x8 __attribute__((ext_vector_type(8)));
typedef float f32x16 __attribute__((ext_vector_type(16)));
typedef float f32x4  __attribute__((ext_vector_type(4)));

#define NPAIR   496            // 32*31/2
#define BATCH_F 512            // floats per batch (32 fields x 16 dim)
#define GB      4              // batches per wave
#define SUB     512            // dwords per batch sub-slice (496 data + 16 trash)
#define SLICE   (GB * SUB)     // 2048 dwords per wave slice

// fp32 -> bf16 round-to-nearest-even (inputs finite normals; no NaN path)
static __device__ __forceinline__ unsigned short f2bf(float f) {
  unsigned u = __float_as_uint(f);
  u += 0x7FFFu + ((u >> 16) & 1u);
  return (unsigned short)(u >> 16);
}

__global__ __launch_bounds__(256, 4)
void ipnn_mfma(const float* __restrict__ x, float* __restrict__ out, int nb) {
  __shared__ __align__(16) float so[4 * SLICE];   // 32 KB/block -> 4 blocks/CU
  const int wave = threadIdx.x >> 6;
  const int lane = threadIdx.x & 63;
  const int m = lane & 31;               // field row this lane loads (= Gram col)
  const int h = lane >> 5;               // k-half: 0 -> k=0..7, 1 -> k=8..15
  const long b0 = ((long)blockIdx.x * 4 + wave) * GB;

  // ---- all global loads issued up front: 8 dwordx4 in flight per wave ----
  f32x4 f[GB][2];
  const int fi = m * 4 + h * 2;          // float4 index within batch
#pragma unroll
  for (int t = 0; t < GB; ++t) {
    long bt = b0 + t;
    if (bt >= nb) bt = nb - 1;           // clamp (grid is exact; safety only)
    const f32x4* gp = (const f32x4*)(x + bt * BATCH_F);
    f[t][0] = gp[fi];
    f[t][1] = gp[fi + 1];
  }

  // ---- batch-invariant scatter addresses, computed once per wave ----
  // C/D layout (m74/m101): col = lane&31, row = (r&3) + 8*(r>>2) + 4*h.
  // G symmetric -> row/col swap immune. Invalid (row>=col) entries are
  // redirected to a trash region via cndmask instead of exec-mask branches.
  float* sw = so + wave * SLICE;
  int addr[16];
#pragma unroll
  for (int r = 0; r < 16; ++r) {
    const int row = (r & 3) + 8 * (r >> 2) + 4 * h;
    const int pidx = ((row * (63 - row)) >> 1) + (m - row - 1);
    addr[r] = (row < m) ? pidx : (NPAIR + (lane & 15));   // trash: 496..511
  }

  // ---- per-batch: convert, MFMA, unconditional LDS scatter ----
#pragma unroll
  for (int t = 0; t < GB; ++t) {
    bf16x8 a;
    a[0] = (short)f2bf(f[t][0].x);
    a[1] = (short)f2bf(f[t][0].y);
    a[2] = (short)f2bf(f[t][0].z);
    a[3] = (short)f2bf(f[t][0].w);
    a[4] = (short)f2bf(f[t][1].x);
    a[5] = (short)f2bf(f[t][1].y);
    a[6] = (short)f2bf(f[t][1].z);
    a[7] = (short)f2bf(f[t][1].w);

    f32x16 acc = {};
    acc = __builtin_amdgcn_mfma_f32_32x32x16_bf16(a, a, acc, 0, 0, 0);

    float* sb = sw + t * SUB;            // t*SUB folds into ds_write imm offset
#pragma unroll
    for (int r = 0; r < 16; ++r) {
      sb[addr[r]] = acc[r];
    }
  }

  // NO __syncthreads: each wave reads back only its own slice; same-wave
  // DS ordering (lgkmcnt) provides the RAW guarantee. Removing the barrier
  // decouples the 4 waves' staggered load arrivals.

  // ---- coalesced readback + store: per batch 62 lanes x 2 float4 ----
  if (lane < 62) {
#pragma unroll
    for (int t = 0; t < GB; ++t) {
      const long bt = b0 + t;
      if (bt >= nb) continue;
      const float* sb = sw + t * SUB;
      f32x4 v0 = *(const f32x4*)(sb + 4 * lane);         // dwords [0,248)
      f32x4 v1 = *(const f32x4*)(sb + 4 * lane + 248);   // dwords [248,496)
      f32x4* op = (f32x4*)(out + bt * NPAIR);
      __builtin_nontemporal_store(v0, op + lane);        // write-once stream:
      __builtin_nontemporal_store(v1, op + lane + 62);   // skip L2 retention
    }
  }
}

extern "C" void kernel_launch(void* const* d_in, const int* in_sizes, int n_in,
                              void* d_out, int out_size, void* d_ws, size_t ws_size,
                              hipStream_t stream) {
  const float* x = (const float*)d_in[0];
  float* out = (float*)d_out;
  const int nb = in_sizes[0] / BATCH_F;       // 16384
  const int grid = (nb + GB * 4 - 1) / (GB * 4);   // 16 batches/block -> 1024
  ipnn_mfma<<<grid, 256, 0, stream>>>(x, out, nb);
}